// Round 4
// baseline (1285.002 us; speedup 1.0000x reference)
//
#include <hip/hip_runtime.h>

static constexpr int NG = 512;       // graphs
static constexpr float LN_EPS = 1e-5f;
static constexpr float BNS = 0.9999950000374997f; // rsqrt(1 + 1e-5) for BatchNorm eval

__device__ __forceinline__ float eluf(float v) { return v > 0.f ? v : expm1f(v); }

// ---------------------------------------------------------------------------
// GEMM: C[n x 256] = act(A[n x (KW4*4)] @ W + b)
// Tile: 32 rows x 256 cols per block (256 threads), LDS = 32 rows * KW4 * 16B.
// Thread (rg = tid>>6, lane = tid&63) computes 8 rows x 4 cols.
// As LDS reads are wave-uniform broadcasts; W reads are coalesced float4,
// software-prefetched one k4 step ahead.
// BD = block-diagonal W [4][64][64]; ACT 0=relu 1=elu; STATS = f64 sum/sumsq.
// __launch_bounds__(256,5): cap VGPR<=102 so 5 waves/SIMD; LDS 32KB -> 5 blk/CU.
// ---------------------------------------------------------------------------
template<int KW4, int ACT, bool BD, bool STATS>
__global__ __launch_bounds__(256, 5)
void gemm_kernel(const float* __restrict__ A, int lda4,
                 const float* __restrict__ W,
                 const float* __restrict__ bias,
                 float* __restrict__ C, int ldc,
                 int n, double* __restrict__ stats)
{
    __shared__ float4 As[32][KW4];
    const int tid = threadIdx.x;
    const int r0 = blockIdx.x << 5;

    for (int i = tid; i < 32 * KW4; i += 256) {
        const int r = i / KW4, c4 = i % KW4;
        const int rr = r0 + r;
        float4 v = make_float4(0.f, 0.f, 0.f, 0.f);
        if (rr < n) v = reinterpret_cast<const float4*>(A)[(size_t)rr * lda4 + c4];
        As[r][c4] = v;
    }
    __syncthreads();

    const int lane = tid & 63;
    const int rg = tid >> 6;      // row group: 8 rows each

    float acc[8][4];
#pragma unroll
    for (int r = 0; r < 8; ++r)
#pragma unroll
        for (int j = 0; j < 4; ++j) acc[r][j] = 0.f;

#define FMA_BLOCK(K4IDX)                                                              \
    _Pragma("unroll")                                                                 \
    for (int r = 0; r < 8; ++r) {                                                     \
        const float4 a = As[rg * 8 + r][K4IDX];                                       \
        acc[r][0] = fmaf(a.x, w0.x, fmaf(a.y, w1.x, fmaf(a.z, w2.x, fmaf(a.w, w3.x, acc[r][0])))); \
        acc[r][1] = fmaf(a.x, w0.y, fmaf(a.y, w1.y, fmaf(a.z, w2.y, fmaf(a.w, w3.y, acc[r][1])))); \
        acc[r][2] = fmaf(a.x, w0.z, fmaf(a.y, w1.z, fmaf(a.z, w2.z, fmaf(a.w, w3.z, acc[r][2])))); \
        acc[r][3] = fmaf(a.x, w0.w, fmaf(a.y, w1.w, fmaf(a.z, w2.w, fmaf(a.w, w3.w, acc[r][3])))); \
    }

    if (!BD) {
        const float4* W4 = reinterpret_cast<const float4*>(W);  // [K][64] float4
        float4 w0 = W4[0 * 64 + lane], w1 = W4[1 * 64 + lane],
               w2 = W4[2 * 64 + lane], w3 = W4[3 * 64 + lane];
        for (int k4 = 0; k4 < KW4; ++k4) {
            const int kn = (k4 + 1 < KW4 ? k4 + 1 : k4) * 4;
            const float4 nw0 = W4[(kn + 0) * 64 + lane];
            const float4 nw1 = W4[(kn + 1) * 64 + lane];
            const float4 nw2 = W4[(kn + 2) * 64 + lane];
            const float4 nw3 = W4[(kn + 3) * 64 + lane];
            FMA_BLOCK(k4)
            w0 = nw0; w1 = nw1; w2 = nw2; w3 = nw3;
        }
    } else {
        const int kc = lane >> 4;   // 64-block index
        const int cl = lane & 15;   // float4 col within block
        const float4* Wb4 = reinterpret_cast<const float4*>(W + kc * 4096); // [64][16] float4
        float4 w0 = Wb4[0 * 16 + cl], w1 = Wb4[1 * 16 + cl],
               w2 = Wb4[2 * 16 + cl], w3 = Wb4[3 * 16 + cl];
        for (int k4 = 0; k4 < 16; ++k4) {
            const int kn = (k4 + 1 < 16 ? k4 + 1 : k4) * 4;
            const float4 nw0 = Wb4[(kn + 0) * 16 + cl];
            const float4 nw1 = Wb4[(kn + 1) * 16 + cl];
            const float4 nw2 = Wb4[(kn + 2) * 16 + cl];
            const float4 nw3 = Wb4[(kn + 3) * 16 + cl];
            const int ka = kc * 16 + k4;
            FMA_BLOCK(ka)
            w0 = nw0; w1 = nw1; w2 = nw2; w3 = nw3;
        }
    }
#undef FMA_BLOCK

    const float4 b4 = reinterpret_cast<const float4*>(bias)[lane];
    double s = 0.0, ss = 0.0;
#pragma unroll
    for (int r = 0; r < 8; ++r) {
        const int rr = r0 + rg * 8 + r;
        if (rr < n) {
            float v0 = acc[r][0] + b4.x, v1 = acc[r][1] + b4.y,
                  v2 = acc[r][2] + b4.z, v3 = acc[r][3] + b4.w;
            if (ACT == 0) { v0 = fmaxf(v0, 0.f); v1 = fmaxf(v1, 0.f); v2 = fmaxf(v2, 0.f); v3 = fmaxf(v3, 0.f); }
            else          { v0 = eluf(v0); v1 = eluf(v1); v2 = eluf(v2); v3 = eluf(v3); }
            reinterpret_cast<float4*>(C + (size_t)rr * ldc)[lane] = make_float4(v0, v1, v2, v3);
            if (STATS) {
                const double d0 = v0, d1 = v1, d2 = v2, d3 = v3;
                s += (d0 + d1) + (d2 + d3);
                ss += (d0 * d0 + d1 * d1) + (d2 * d2 + d3 * d3);
            }
        }
    }
    if (STATS) {
        for (int o = 32; o; o >>= 1) { s += __shfl_down(s, o, 64); ss += __shfl_down(ss, o, 64); }
        if (lane == 0) { unsafeAtomicAdd(&stats[0], s); unsafeAtomicAdd(&stats[1], ss); }
    }
}

// ---------------------------------------------------------------------------
// CSR construction (by destination), rebuilt every call (no cross-call state)
// ---------------------------------------------------------------------------
__global__ void count_kernel(const int* __restrict__ dst, int* __restrict__ cnt, int nE)
{
    const int e = blockIdx.x * 256 + threadIdx.x;
    if (e < nE) atomicAdd(&cnt[dst[e]], 1);
}

__global__ __launch_bounds__(1024)
void scan_kernel(const int* __restrict__ cnt, int* __restrict__ rowptr, int n)
{
    __shared__ int part[1024];
    const int t = threadIdx.x;
    const int chunk = (n + 1023) / 1024;
    const int i0 = min(t * chunk, n), i1 = min(i0 + chunk, n);
    int s = 0;
    for (int i = i0; i < i1; ++i) s += cnt[i];
    part[t] = s;
    __syncthreads();
    for (int o = 1; o < 1024; o <<= 1) {
        const int v = (t >= o) ? part[t - o] : 0;
        __syncthreads();
        part[t] += v;
        __syncthreads();
    }
    int base = (t == 0) ? 0 : part[t - 1];
    for (int i = i0; i < i1; ++i) { rowptr[i] = base; base += cnt[i]; }
    if (t == 1023) rowptr[n] = part[1023];
}

__global__ void fill_kernel(const int* __restrict__ src, const int* __restrict__ dst,
                            int* __restrict__ cursor, int* __restrict__ es, int nE)
{
    const int e = blockIdx.x * 256 + threadIdx.x;
    if (e >= nE) return;
    const int p = atomicAdd(&cursor[dst[e]], 1);
    es[p] = src[e];
}

// ---------------------------------------------------------------------------
// Layer-0 gather (prep fused): tB[i] = 2*h_i + (2+deg_i)*vn + sum_{j in in(i)} h_j
// h rows live in gr slice0 (row stride 768 floats = 192 float4)
// ---------------------------------------------------------------------------
__global__ __launch_bounds__(256)
void gather0_kernel(const float* __restrict__ gr, const int* __restrict__ rowptr,
                    const int* __restrict__ es, const float* __restrict__ vn_emb,
                    float* __restrict__ tB, int n)
{
    const int node = blockIdx.x * 4 + (threadIdx.x >> 6);
    if (node >= n) return;
    const int lane = threadIdx.x & 63;
    const float4* G4 = reinterpret_cast<const float4*>(gr);
    const float4 vn = reinterpret_cast<const float4*>(vn_emb)[lane];
    const float4 own = G4[(size_t)node * 192 + lane];
    const int b = rowptr[node], e = rowptr[node + 1];
    const float cvn = (float)(2 + (e - b));
    float4 acc = make_float4(fmaf(cvn, vn.x, 2.f * own.x), fmaf(cvn, vn.y, 2.f * own.y),
                             fmaf(cvn, vn.z, 2.f * own.z), fmaf(cvn, vn.w, 2.f * own.w));
    int i = b;
    for (; i + 4 <= e; i += 4) {
        const int s0 = es[i], s1 = es[i + 1], s2 = es[i + 2], s3 = es[i + 3];
        const float4 v0 = G4[(size_t)s0 * 192 + lane];
        const float4 v1 = G4[(size_t)s1 * 192 + lane];
        const float4 v2 = G4[(size_t)s2 * 192 + lane];
        const float4 v3 = G4[(size_t)s3 * 192 + lane];
        acc.x += (v0.x + v1.x) + (v2.x + v3.x);
        acc.y += (v0.y + v1.y) + (v2.y + v3.y);
        acc.z += (v0.z + v1.z) + (v2.z + v3.z);
        acc.w += (v0.w + v1.w) + (v2.w + v3.w);
    }
    for (; i < e; ++i) {
        const int s = es[i];
        const float4 v = G4[(size_t)s * 192 + lane];
        acc.x += v.x; acc.y += v.y; acc.z += v.z; acc.w += v.w;
    }
    reinterpret_cast<float4*>(tB)[(size_t)node * 64 + lane] = acc;
}

// Generic gather: tB[i] = 2*tA[i] + sum_{j in in(i)} tA[j]  (tA row = 64 float4)
__global__ __launch_bounds__(256)
void gather_kernel(const float* __restrict__ tA, const int* __restrict__ rowptr,
                   const int* __restrict__ es, float* __restrict__ tB, int n)
{
    const int node = blockIdx.x * 4 + (threadIdx.x >> 6);
    if (node >= n) return;
    const int lane = threadIdx.x & 63;
    const float4* A4 = reinterpret_cast<const float4*>(tA);
    const float4 own = A4[(size_t)node * 64 + lane];
    float4 acc = make_float4(2.f * own.x, 2.f * own.y, 2.f * own.z, 2.f * own.w);
    const int b = rowptr[node], e = rowptr[node + 1];
    int i = b;
    for (; i + 4 <= e; i += 4) {
        const int s0 = es[i], s1 = es[i + 1], s2 = es[i + 2], s3 = es[i + 3];
        const float4 v0 = A4[(size_t)s0 * 64 + lane];
        const float4 v1 = A4[(size_t)s1 * 64 + lane];
        const float4 v2 = A4[(size_t)s2 * 64 + lane];
        const float4 v3 = A4[(size_t)s3 * 64 + lane];
        acc.x += (v0.x + v1.x) + (v2.x + v3.x);
        acc.y += (v0.y + v1.y) + (v2.y + v3.y);
        acc.z += (v0.z + v1.z) + (v2.z + v3.z);
        acc.w += (v0.w + v1.w) + (v2.w + v3.w);
    }
    for (; i < e; ++i) {
        const int s = es[i];
        const float4 v = A4[(size_t)s * 64 + lane];
        acc.x += v.x; acc.y += v.y; acc.z += v.z; acc.w += v.w;
    }
    reinterpret_cast<float4*>(tB)[(size_t)node * 64 + lane] = acc;
}

// Layer-1 prep: tA = gr1 + vn2[batch[row]]
__global__ void prep1_kernel(const float* __restrict__ gr, const float* __restrict__ vn2,
                             const int* __restrict__ batch,
                             float* __restrict__ tA, int n)
{
    const size_t i4 = (size_t)blockIdx.x * blockDim.x + threadIdx.x;
    if (i4 >= (size_t)n * 64) return;
    const int row = (int)(i4 >> 6), c4 = (int)(i4 & 63);
    const int g = batch[row];  // wave-uniform (64 consecutive i4 share row)
    const float4 e = reinterpret_cast<const float4*>(vn2 + (size_t)g * 256)[c4];
    const float4 v = reinterpret_cast<const float4*>(gr)[(size_t)row * 192 + 64 + c4];
    reinterpret_cast<float4*>(tA)[i4] = make_float4(v.x + e.x, v.y + e.y, v.z + e.z, v.w + e.w);
}

// Graph boundaries (batch is sorted): off[g] = lower_bound(batch, g), off[NG] = n
__global__ void offsets_kernel(const int* __restrict__ batch, int n, int* __restrict__ off)
{
    const int g = blockIdx.x * blockDim.x + threadIdx.x;
    if (g > NG) return;
    int lo = 0, hi = n;
    while (lo < hi) { const int mid = (lo + hi) >> 1; if (batch[mid] < g) lo = mid + 1; else hi = mid; }
    off[g] = lo;
}

__global__ void finalize_kernel(const double* __restrict__ sacc, float* __restrict__ sfin, double M)
{
    const double mean = sacc[0] / M;
    double var = sacc[1] / M - mean * mean;
    if (var < 0.0) var = 0.0;
    sfin[0] = (float)mean;
    sfin[1] = (float)(1.0 / sqrt(var + (double)LN_EPS));
}

// grs points at gr + slice*256 (row stride 768): grs_row4[row*192 + c4]
__global__ void norm_kernel(const float* __restrict__ tB, const float* __restrict__ sfin,
                            float* __restrict__ grs, int n)
{
    const size_t i4 = (size_t)blockIdx.x * blockDim.x + threadIdx.x;
    if (i4 >= (size_t)n * 64) return;
    const float m = sfin[0], rs = sfin[1];
    const int row = (int)(i4 >> 6), c4 = (int)(i4 & 63);
    const float4 v = reinterpret_cast<const float4*>(tB)[i4];
    reinterpret_cast<float4*>(grs)[(size_t)row * 192 + c4] =
        make_float4((v.x - m) * rs, (v.y - m) * rs, (v.z - m) * rs, (v.w - m) * rs);
}

// vt[g] = sum over graph-g rows of gr slice0 + vn_emb
__global__ __launch_bounds__(256)
void vtsum_kernel(const float* __restrict__ gr, const int* __restrict__ off,
                  const float* __restrict__ vn_emb, float* __restrict__ vt)
{
    const int g = blockIdx.x, t = threadIdx.x;
    const int i0 = off[g], i1 = off[g + 1];
    float s = 0.f;
    for (int i = i0; i < i1; ++i) s += gr[(size_t)i * 768 + t];
    vt[(size_t)g * 256 + t] = s + vn_emb[t];
}

__global__ __launch_bounds__(256)
void vn1_kernel(const float* __restrict__ vt, const float* __restrict__ W,
                const float* __restrict__ b, float* __restrict__ vn1)
{
    __shared__ float row[256];
    const int g = blockIdx.x, t = threadIdx.x;
    row[t] = vt[(size_t)g * 256 + t];
    __syncthreads();
    float a0 = 0.f, a1 = 0.f;
    for (int k = 0; k < 256; ++k) {
        const float rv = row[k];
        a0 = fmaf(rv, W[(size_t)k * 512 + t], a0);
        a1 = fmaf(rv, W[(size_t)k * 512 + 256 + t], a1);
    }
    vn1[(size_t)g * 512 + t]       = fmaxf((a0 + b[t]) * BNS, 0.f);
    vn1[(size_t)g * 512 + 256 + t] = fmaxf((a1 + b[256 + t]) * BNS, 0.f);
}

__global__ __launch_bounds__(256)
void vn2_kernel(const float* __restrict__ vn1, const float* __restrict__ W,
                const float* __restrict__ b, float* __restrict__ vn2)
{
    __shared__ float row[512];
    const int g = blockIdx.x, t = threadIdx.x;
    row[t]       = vn1[(size_t)g * 512 + t];
    row[t + 256] = vn1[(size_t)g * 512 + 256 + t];
    __syncthreads();
    float a = 0.f;
    for (int k = 0; k < 512; ++k) a = fmaf(row[k], W[(size_t)k * 256 + t], a);
    vn2[(size_t)g * 256 + t] = fmaxf((a + b[t]) * BNS, 0.f);
}

// segment max + mean over gr [n x 768] -> readb [NG x 1536] = [max | mean]
__global__ __launch_bounds__(256)
void pool_kernel(const float* __restrict__ gr, const int* __restrict__ off,
                 float* __restrict__ readb)
{
    const int g = blockIdx.x, t = threadIdx.x;
    const int i0 = off[g], i1 = off[g + 1];
    float m0 = -__builtin_inff(), m1 = m0, m2 = m0;
    float s0 = 0.f, s1 = 0.f, s2 = 0.f;
    for (int i = i0; i < i1; ++i) {
        const float* p = gr + (size_t)i * 768;
        const float v0 = p[t], v1 = p[t + 256], v2 = p[t + 512];
        m0 = fmaxf(m0, v0); m1 = fmaxf(m1, v1); m2 = fmaxf(m2, v2);
        s0 += v0; s1 += v1; s2 += v2;
    }
    const float inv = 1.f / fmaxf((float)(i1 - i0), 1.f);
    float* rb = readb + (size_t)g * 1536;
    rb[t] = m0; rb[t + 256] = m1; rb[t + 512] = m2;
    rb[768 + t] = s0 * inv; rb[768 + 256 + t] = s1 * inv; rb[768 + 512 + t] = s2 * inv;
}

// x5 = elu(readb @ loW + lob), 8 graphs per block
__global__ __launch_bounds__(256)
void outg_kernel(const float* __restrict__ readb, const float* __restrict__ W,
                 const float* __restrict__ b, float* __restrict__ x5)
{
    __shared__ float rows[8][1536];
    const int g0 = blockIdx.x * 8, t = threadIdx.x;
    for (int i = t; i < 8 * 1536; i += 256) rows[i / 1536][i % 1536] = readb[(size_t)g0 * 1536 + i];
    __syncthreads();
    float acc[8];
#pragma unroll
    for (int r = 0; r < 8; ++r) acc[r] = 0.f;
    for (int k = 0; k < 1536; ++k) {
        const float wv = W[(size_t)k * 256 + t];
#pragma unroll
        for (int r = 0; r < 8; ++r) acc[r] = fmaf(rows[r][k], wv, acc[r]);
    }
    const float bb = b[t];
#pragma unroll
    for (int r = 0; r < 8; ++r) x5[(size_t)(g0 + r) * 256 + t] = eluf(acc[r] + bb);
}

__global__ __launch_bounds__(64)
void logits_kernel(const float* __restrict__ x5, const float* __restrict__ W,
                   const float* __restrict__ b, float* __restrict__ out)
{
    const int g = blockIdx.x, l = threadIdx.x;
    const float4 v   = reinterpret_cast<const float4*>(x5 + (size_t)g * 256)[l];
    const float4 w01 = reinterpret_cast<const float4*>(W)[l * 2];
    const float4 w23 = reinterpret_cast<const float4*>(W)[l * 2 + 1];
    float p0 = v.x * w01.x + v.y * w01.z + v.z * w23.x + v.w * w23.z;
    float p1 = v.x * w01.y + v.y * w01.w + v.z * w23.y + v.w * w23.w;
    for (int o = 32; o; o >>= 1) { p0 += __shfl_down(p0, o, 64); p1 += __shfl_down(p1, o, 64); }
    if (l == 0) {
        const float z0 = p0 + b[0], z1 = p1 + b[1];
        const float m = fmaxf(z0, z1);
        const float lse = m + logf(expf(z0 - m) + expf(z1 - m));
        out[(size_t)g * 2 + 0] = z0 - lse;
        out[(size_t)g * 2 + 1] = z1 - lse;
    }
}

__global__ __launch_bounds__(192)
void ssl_kernel(const float* __restrict__ x5, const float* __restrict__ dW,
                const float* __restrict__ db, float* __restrict__ out)
{
    const int g = blockIdx.x, t = threadIdx.x;
    const int h = t >> 6, l = t & 63;
    float p = x5[(size_t)g * 256 + h * 64 + l] * dW[h * 64 + l];
    for (int o = 32; o; o >>= 1) p += __shfl_down(p, o, 64);
    if (l == 0) {
        const float z = p + db[h];
        out[(size_t)g * 3 + h] = 0.05f + 0.35f / (1.f + expf(-z));
    }
}

// ---------------------------------------------------------------------------
extern "C" void kernel_launch(void* const* d_in, const int* in_sizes, int n_in,
                              void* d_out, int out_size, void* d_ws, size_t ws_size,
                              hipStream_t stream)
{
    const float* x      = (const float*)d_in[0];
    const int*   eidx   = (const int*)d_in[1];
    const int*   batch  = (const int*)d_in[2];
    const float* lin1_W = (const float*)d_in[3];
    const float* lin1_b = (const float*)d_in[4];
    const float* g0W1   = (const float*)d_in[5];
    const float* g0b1   = (const float*)d_in[6];
    const float* g0W2   = (const float*)d_in[7];
    const float* g0b2   = (const float*)d_in[8];
    const float* g1W1   = (const float*)d_in[9];
    const float* g1b1   = (const float*)d_in[10];
    const float* g1W2   = (const float*)d_in[11];
    const float* g1b2   = (const float*)d_in[12];
    const float* vn_emb = (const float*)d_in[13];
    const float* vnW1   = (const float*)d_in[14];
    const float* vnb1   = (const float*)d_in[15];
    const float* vnW2   = (const float*)d_in[16];
    const float* vnb2   = (const float*)d_in[17];
    const float* loW    = (const float*)d_in[18];
    const float* lob    = (const float*)d_in[19];
    const float* clsW   = (const float*)d_in[20];
    const float* clsb   = (const float*)d_in[21];
    const float* dhW    = (const float*)d_in[22];
    const float* dhb    = (const float*)d_in[23];

    const int N = in_sizes[2];        // 50000 nodes
    const int E = in_sizes[1] / 2;    // 800000 edges
    const int* esrc = eidx;
    const int* edst = eidx + E;

    float* out = (float*)d_out;
    float* out_logits = out;                                     // [NG,2]
    float* out_x5     = out + (size_t)NG * 2;                    // [NG,256]
    float* out_ssl    = out + (size_t)NG * 2 + (size_t)NG * 256; // [NG,3]

    // --- workspace carve (256B aligned slots) ---
    char* p = (char*)d_ws;
    auto carve = [&](size_t bytes) { char* r = p; p += (bytes + 255) & ~(size_t)255; return (void*)r; };
    double* sacc   = (double*)carve(4 * sizeof(double));            // LN stats accum (2 slots x 2)
    float*  sfin   = (float*) carve(4 * sizeof(float));             // finalized mean/rsqrt
    int*    goff   = (int*)   carve((NG + 1) * sizeof(int));
    int*    cnt    = (int*)   carve((size_t)N * sizeof(int));       // in-degree counts
    int*    rowptr = (int*)   carve((size_t)(N + 1) * sizeof(int)); // CSR row offsets
    int*    cursor = (int*)   carve((size_t)N * sizeof(int));       // fill cursors
    int*    es     = (int*)   carve((size_t)E * sizeof(int));       // CSR column (src) indices
    float*  gr     = (float*) carve((size_t)N * 768 * sizeof(float)); // [gr0|gr1|gr2]
    float*  tA     = (float*) carve((size_t)N * 256 * sizeof(float));
    float*  tB     = (float*) carve((size_t)N * 256 * sizeof(float));
    float*  vt     = (float*) carve((size_t)NG * 256 * sizeof(float));
    float*  vn1    = (float*) carve((size_t)NG * 512 * sizeof(float));
    float*  vn2    = (float*) carve((size_t)NG * 256 * sizeof(float));
    float*  readb  = (float*) carve((size_t)NG * 1536 * sizeof(float));

    hipMemsetAsync(sacc, 0, 4 * sizeof(double), stream);
    hipMemsetAsync(cnt, 0, (size_t)N * sizeof(int), stream);

    const int gemmGrid = (N + 31) / 32;
    const int n4 = N * 64;                 // float4 count of an [N,256] buffer
    const int vecGrid = (n4 + 255) / 256;
    const int eGrid = (E + 255) / 256;
    const int gatherGrid = (N + 3) / 4;

    // ---- CSR build (shared by both layers) ----
    count_kernel<<<eGrid, 256, 0, stream>>>(edst, cnt, E);
    scan_kernel<<<1, 1024, 0, stream>>>(cnt, rowptr, N);
    hipMemcpyAsync(cursor, rowptr, (size_t)N * sizeof(int), hipMemcpyDeviceToDevice, stream);
    fill_kernel<<<eGrid, 256, 0, stream>>>(esrc, edst, cursor, es, E);

    // h0 = elu(x @ lin1_W + b) -> gr slice0
    gemm_kernel<32, 1, false, false><<<gemmGrid, 256, 0, stream>>>(x, 32, lin1_W, lin1_b, gr, 768, N, nullptr);
    offsets_kernel<<<3, 256, 0, stream>>>(batch, N, goff);

    // ---- layer 0 (prep fused into gather0) ----
    gather0_kernel<<<gatherGrid, 256, 0, stream>>>(gr, rowptr, es, vn_emb, tB, N);
    gemm_kernel<64, 0, false, false><<<gemmGrid, 256, 0, stream>>>(tB, 64, g0W1, g0b1, tA, 256, N, nullptr);
    gemm_kernel<64, 1, false, true ><<<gemmGrid, 256, 0, stream>>>(tA, 64, g0W2, g0b2, tB, 256, N, sacc);
    finalize_kernel<<<1, 1, 0, stream>>>(sacc, sfin, (double)N * 256.0);
    norm_kernel<<<vecGrid, 256, 0, stream>>>(tB, sfin, gr + 256, N);

    // ---- virtual node update ----
    vtsum_kernel<<<NG, 256, 0, stream>>>(gr, goff, vn_emb, vt);
    vn1_kernel<<<NG, 256, 0, stream>>>(vt, vnW1, vnb1, vn1);
    vn2_kernel<<<NG, 256, 0, stream>>>(vn1, vnW2, vnb2, vn2);

    // ---- layer 1 (block-diagonal GIN) ----
    prep1_kernel<<<vecGrid, 256, 0, stream>>>(gr, vn2, batch, tA, N);
    gather_kernel<<<gatherGrid, 256, 0, stream>>>(tA, rowptr, es, tB, N);
    gemm_kernel<64, 0, true, false><<<gemmGrid, 256, 0, stream>>>(tB, 64, g1W1, g1b1, tA, 256, N, nullptr);
    gemm_kernel<64, 1, true, true ><<<gemmGrid, 256, 0, stream>>>(tA, 64, g1W2, g1b2, tB, 256, N, sacc + 2);
    finalize_kernel<<<1, 1, 0, stream>>>(sacc + 2, sfin + 2, (double)N * 256.0);
    norm_kernel<<<vecGrid, 256, 0, stream>>>(tB, sfin + 2, gr + 512, N);

    // ---- readout ----
    pool_kernel<<<NG, 256, 0, stream>>>(gr, goff, readb);
    outg_kernel<<<NG / 8, 256, 0, stream>>>(readb, loW, lob, out_x5);
    logits_kernel<<<NG, 64, 0, stream>>>(out_x5, clsW, clsb, out_logits);
    ssl_kernel<<<NG, 192, 0, stream>>>(out_x5, dhW, dhb, out_ssl);
}

// Round 5
// 949.138 us; speedup vs baseline: 1.3539x; 1.3539x over previous
//
#include <hip/hip_runtime.h>

static constexpr int NG = 512;       // graphs
static constexpr float LN_EPS = 1e-5f;
static constexpr float BNS = 0.9999950000374997f; // rsqrt(1 + 1e-5) for BatchNorm eval

__device__ __forceinline__ float eluf(float v) { return v > 0.f ? v : expm1f(v); }

typedef __attribute__((ext_vector_type(8))) short bf16x8;
typedef __attribute__((ext_vector_type(4))) float f32x4;

__device__ __forceinline__ ushort f2b(float f) {   // f32 -> bf16 RNE
    union { float f; unsigned u; } v; v.f = f;
    const unsigned u = v.u;
    return (ushort)((u + 0x7FFFu + ((u >> 16) & 1u)) >> 16);
}
__device__ __forceinline__ float b2f(ushort b) {
    union { unsigned u; float f; } v; v.u = ((unsigned)b) << 16;
    return v.f;
}

// ---------------------------------------------------------------------------
// MFMA GEMM: C[n x 256] = act(A[n x K] @ W + b), A bf16 row-major (ldab = K),
// Wt bf16 [256 cols][K] (dense) or [4][64 colw][64 k] (BD).
// Block = 256 thr = 4 waves; wave w owns rows blockIdx*64 + w*16 .. +16.
// mfma_f32_16x16x32_bf16: A-frag lane l = A[row0+(l&15)][k0+(l>>4)*8 ..+8];
// B-frag lane l = Wt[ct*16+(l&15)][k0+(l>>4)*8 ..+8];
// D lane l reg r = C[row0+(l>>4)*4+r][ct*16+(l&15)]  (m89-verified layout).
// ---------------------------------------------------------------------------
template<int KT, int ACT, bool BD, bool STATS, bool WF32, bool WB16>
__global__ __launch_bounds__(256)
void mgemm_kernel(const ushort* __restrict__ Ab, int ldab,
                  const ushort* __restrict__ Wt,
                  const float* __restrict__ bias,
                  float* __restrict__ Cf, int ldc,
                  ushort* __restrict__ Cb,
                  int n, double* __restrict__ stats)
{
    const int tid = threadIdx.x;
    const int lane = tid & 63;
    const int wv = tid >> 6;
    const int row0 = blockIdx.x * 64 + wv * 16;
    const int rA = min(row0 + (lane & 15), n - 1);
    const int koff = (lane >> 4) * 8;
    const int colL = lane & 15;

    float s = 0.f, ss = 0.f;

    auto epi = [&](int ct, const f32x4& c) {
        const float bv = bias[ct * 16 + colL];
#pragma unroll
        for (int r = 0; r < 4; ++r) {
            const int row = row0 + ((lane >> 4) << 2) + r;
            if (row < n) {
                float v = c[r] + bv;
                v = (ACT == 0) ? fmaxf(v, 0.f) : eluf(v);
                if constexpr (WF32) Cf[(size_t)row * ldc + ct * 16 + colL] = v;
                if constexpr (WB16) Cb[(size_t)row * 256 + ct * 16 + colL] = f2b(v);
                if constexpr (STATS) { s += v; ss += v * v; }
            }
        }
    };

    if constexpr (!BD) {
        bf16x8 af[KT];
        const ushort* ap = Ab + (size_t)rA * ldab + koff;
#pragma unroll
        for (int kk = 0; kk < KT; ++kk)
            af[kk] = *reinterpret_cast<const bf16x8*>(ap + kk * 32);
#pragma unroll
        for (int ct = 0; ct < 16; ct += 2) {
            const ushort* w0p = Wt + (size_t)((ct    ) * 16 + colL) * (KT * 32) + koff;
            const ushort* w1p = Wt + (size_t)((ct + 1) * 16 + colL) * (KT * 32) + koff;
            f32x4 c0 = {0.f, 0.f, 0.f, 0.f}, c1 = {0.f, 0.f, 0.f, 0.f};
#pragma unroll
            for (int kk = 0; kk < KT; ++kk) {
                c0 = __builtin_amdgcn_mfma_f32_16x16x32_bf16(
                        af[kk], *reinterpret_cast<const bf16x8*>(w0p + kk * 32), c0, 0, 0, 0);
                c1 = __builtin_amdgcn_mfma_f32_16x16x32_bf16(
                        af[kk], *reinterpret_cast<const bf16x8*>(w1p + kk * 32), c1, 0, 0, 0);
            }
            epi(ct, c0);
            epi(ct + 1, c1);
        }
    } else {
        const size_t abase = (size_t)rA * 256;
#pragma unroll
        for (int ch = 0; ch < 4; ++ch) {
            const bf16x8 a0 = *reinterpret_cast<const bf16x8*>(Ab + abase + ch * 64 + koff);
            const bf16x8 a1 = *reinterpret_cast<const bf16x8*>(Ab + abase + ch * 64 + 32 + koff);
#pragma unroll
            for (int cc = 0; cc < 4; cc += 2) {
                const int ct = ch * 4 + cc;
                const ushort* w0p = Wt + ch * 4096 + ((cc    ) * 16 + colL) * 64 + koff;
                const ushort* w1p = Wt + ch * 4096 + ((cc + 1) * 16 + colL) * 64 + koff;
                f32x4 c0 = {0.f, 0.f, 0.f, 0.f}, c1 = {0.f, 0.f, 0.f, 0.f};
                c0 = __builtin_amdgcn_mfma_f32_16x16x32_bf16(a0, *reinterpret_cast<const bf16x8*>(w0p), c0, 0, 0, 0);
                c0 = __builtin_amdgcn_mfma_f32_16x16x32_bf16(a1, *reinterpret_cast<const bf16x8*>(w0p + 32), c0, 0, 0, 0);
                c1 = __builtin_amdgcn_mfma_f32_16x16x32_bf16(a0, *reinterpret_cast<const bf16x8*>(w1p), c1, 0, 0, 0);
                c1 = __builtin_amdgcn_mfma_f32_16x16x32_bf16(a1, *reinterpret_cast<const bf16x8*>(w1p + 32), c1, 0, 0, 0);
                epi(ct, c0);
                epi(ct + 1, c1);
            }
        }
    }

    if constexpr (STATS) {
        double ds = (double)s, dss = (double)ss;
        for (int o = 32; o; o >>= 1) { ds += __shfl_down(ds, o, 64); dss += __shfl_down(dss, o, 64); }
        if (lane == 0) { unsafeAtomicAdd(&stats[0], ds); unsafeAtomicAdd(&stats[1], dss); }
    }
}

// ---------------------------------------------------------------------------
// Weight prep: f32 -> bf16 transposed
// ---------------------------------------------------------------------------
__global__ void wt_dense_kernel(const float* __restrict__ W, ushort* __restrict__ Wt, int K)
{
    const int idx = blockIdx.x * 256 + threadIdx.x;
    if (idx >= 256 * K) return;
    const int c = idx / K, k = idx - c * K;
    Wt[idx] = f2b(W[(size_t)k * 256 + c]);
}

__global__ void wt_bd_kernel(const float* __restrict__ W, ushort* __restrict__ Wt)
{
    const int idx = blockIdx.x * 256 + threadIdx.x;
    if (idx >= 16384) return;
    const int ch = idx >> 12, r = idx & 4095, cw = r >> 6, k = r & 63;
    Wt[idx] = f2b(W[ch * 4096 + k * 64 + cw]);
}

__global__ void cvt_kernel(const float* __restrict__ in, ushort* __restrict__ out, int n4)
{
    const int i = blockIdx.x * 256 + threadIdx.x;
    if (i >= n4) return;
    const float4 v = reinterpret_cast<const float4*>(in)[i];
    reinterpret_cast<ushort4*>(out)[i] = make_ushort4(f2b(v.x), f2b(v.y), f2b(v.z), f2b(v.w));
}

// ---------------------------------------------------------------------------
// CSR construction (by destination), rebuilt every call
// ---------------------------------------------------------------------------
__global__ void count_kernel(const int* __restrict__ dst, int* __restrict__ cnt, int nE)
{
    const int e = blockIdx.x * 256 + threadIdx.x;
    if (e < nE) atomicAdd(&cnt[dst[e]], 1);
}

__global__ __launch_bounds__(1024)
void scan_kernel(const int* __restrict__ cnt, int* __restrict__ rowptr, int n)
{
    __shared__ int part[1024];
    const int t = threadIdx.x;
    const int chunk = (n + 1023) / 1024;
    const int i0 = min(t * chunk, n), i1 = min(i0 + chunk, n);
    int s = 0;
    for (int i = i0; i < i1; ++i) s += cnt[i];
    part[t] = s;
    __syncthreads();
    for (int o = 1; o < 1024; o <<= 1) {
        const int v = (t >= o) ? part[t - o] : 0;
        __syncthreads();
        part[t] += v;
        __syncthreads();
    }
    int base = (t == 0) ? 0 : part[t - 1];
    for (int i = i0; i < i1; ++i) { rowptr[i] = base; base += cnt[i]; }
    if (t == 1023) rowptr[n] = part[1023];
}

__global__ void fill_kernel(const int* __restrict__ src, const int* __restrict__ dst,
                            int* __restrict__ cursor, int* __restrict__ es, int nE)
{
    const int e = blockIdx.x * 256 + threadIdx.x;
    if (e >= nE) return;
    const int p = atomicAdd(&cursor[dst[e]], 1);
    es[p] = src[e];
}

// ---------------------------------------------------------------------------
// Layer-0 gather (vn fold): ob[i] = bf16( 2*h_i + (2+deg_i)*vn + sum_j h_j )
// bf16 rows of 256: lane handles 4 cols (ushort4 = 8B)
// ---------------------------------------------------------------------------
__global__ __launch_bounds__(256)
void gather0b_kernel(const ushort* __restrict__ hb, const int* __restrict__ rowptr,
                     const int* __restrict__ es, const float* __restrict__ vn_emb,
                     ushort* __restrict__ ob, int n)
{
    const int node = blockIdx.x * 4 + (threadIdx.x >> 6);
    if (node >= n) return;
    const int lane = threadIdx.x & 63;
    const ushort4* H4 = reinterpret_cast<const ushort4*>(hb);
    const ushort4 o = H4[(size_t)node * 64 + lane];
    const int b = rowptr[node], e = rowptr[node + 1];
    const float4 vn = reinterpret_cast<const float4*>(vn_emb)[lane];
    const float cv = (float)(2 + (e - b));
    float a0 = fmaf(cv, vn.x, 2.f * b2f(o.x));
    float a1 = fmaf(cv, vn.y, 2.f * b2f(o.y));
    float a2 = fmaf(cv, vn.z, 2.f * b2f(o.z));
    float a3 = fmaf(cv, vn.w, 2.f * b2f(o.w));
    int i = b;
    for (; i + 2 <= e; i += 2) {
        const ushort4 v0 = H4[(size_t)es[i] * 64 + lane];
        const ushort4 v1 = H4[(size_t)es[i + 1] * 64 + lane];
        a0 += b2f(v0.x) + b2f(v1.x);
        a1 += b2f(v0.y) + b2f(v1.y);
        a2 += b2f(v0.z) + b2f(v1.z);
        a3 += b2f(v0.w) + b2f(v1.w);
    }
    for (; i < e; ++i) {
        const ushort4 v = H4[(size_t)es[i] * 64 + lane];
        a0 += b2f(v.x); a1 += b2f(v.y); a2 += b2f(v.z); a3 += b2f(v.w);
    }
    reinterpret_cast<ushort4*>(ob)[(size_t)node * 64 + lane] =
        make_ushort4(f2b(a0), f2b(a1), f2b(a2), f2b(a3));
}

// Generic gather: ob[i] = bf16( 2*t_i + sum_j t_j )
__global__ __launch_bounds__(256)
void gatherb_kernel(const ushort* __restrict__ tb, const int* __restrict__ rowptr,
                    const int* __restrict__ es, ushort* __restrict__ ob, int n)
{
    const int node = blockIdx.x * 4 + (threadIdx.x >> 6);
    if (node >= n) return;
    const int lane = threadIdx.x & 63;
    const ushort4* H4 = reinterpret_cast<const ushort4*>(tb);
    const ushort4 o = H4[(size_t)node * 64 + lane];
    float a0 = 2.f * b2f(o.x), a1 = 2.f * b2f(o.y), a2 = 2.f * b2f(o.z), a3 = 2.f * b2f(o.w);
    const int b = rowptr[node], e = rowptr[node + 1];
    int i = b;
    for (; i + 2 <= e; i += 2) {
        const ushort4 v0 = H4[(size_t)es[i] * 64 + lane];
        const ushort4 v1 = H4[(size_t)es[i + 1] * 64 + lane];
        a0 += b2f(v0.x) + b2f(v1.x);
        a1 += b2f(v0.y) + b2f(v1.y);
        a2 += b2f(v0.z) + b2f(v1.z);
        a3 += b2f(v0.w) + b2f(v1.w);
    }
    for (; i < e; ++i) {
        const ushort4 v = H4[(size_t)es[i] * 64 + lane];
        a0 += b2f(v.x); a1 += b2f(v.y); a2 += b2f(v.z); a3 += b2f(v.w);
    }
    reinterpret_cast<ushort4*>(ob)[(size_t)node * 64 + lane] =
        make_ushort4(f2b(a0), f2b(a1), f2b(a2), f2b(a3));
}

// Graph boundaries (batch is sorted)
__global__ void offsets_kernel(const int* __restrict__ batch, int n, int* __restrict__ off)
{
    const int g = blockIdx.x * blockDim.x + threadIdx.x;
    if (g > NG) return;
    int lo = 0, hi = n;
    while (lo < hi) { const int mid = (lo + hi) >> 1; if (batch[mid] < g) lo = mid + 1; else hi = mid; }
    off[g] = lo;
}

__global__ void finalize_kernel(const double* __restrict__ sacc, float* __restrict__ sfin, double M)
{
    const double mean = sacc[0] / M;
    double var = sacc[1] / M - mean * mean;
    if (var < 0.0) var = 0.0;
    sfin[0] = (float)mean;
    sfin[1] = (float)(1.0 / sqrt(var + (double)LN_EPS));
}

// LN normalize (bf16 in), write gr slice f32 AND bf16(z + vn2[batch]) for layer 1
__global__ void norm0f_kernel(const ushort* __restrict__ zb, const float* __restrict__ sfin,
                              const float* __restrict__ vn2, const int* __restrict__ batch,
                              float* __restrict__ grs, ushort* __restrict__ tb, int n)
{
    const size_t i4 = (size_t)blockIdx.x * blockDim.x + threadIdx.x;
    if (i4 >= (size_t)n * 64) return;
    const float m = sfin[0], rs = sfin[1];
    const int row = (int)(i4 >> 6), c4 = (int)(i4 & 63);
    const ushort4 u = reinterpret_cast<const ushort4*>(zb)[i4];
    const float z0 = (b2f(u.x) - m) * rs, z1 = (b2f(u.y) - m) * rs,
                z2 = (b2f(u.z) - m) * rs, z3 = (b2f(u.w) - m) * rs;
    reinterpret_cast<float4*>(grs)[(size_t)row * 192 + c4] = make_float4(z0, z1, z2, z3);
    const int g = batch[row];
    const float4 e = reinterpret_cast<const float4*>(vn2 + (size_t)g * 256)[c4];
    reinterpret_cast<ushort4*>(tb)[i4] =
        make_ushort4(f2b(z0 + e.x), f2b(z1 + e.y), f2b(z2 + e.z), f2b(z3 + e.w));
}

// LN normalize (bf16 in), write gr slice f32 only
__global__ void norm1b_kernel(const ushort* __restrict__ zb, const float* __restrict__ sfin,
                              float* __restrict__ grs, int n)
{
    const size_t i4 = (size_t)blockIdx.x * blockDim.x + threadIdx.x;
    if (i4 >= (size_t)n * 64) return;
    const float m = sfin[0], rs = sfin[1];
    const int row = (int)(i4 >> 6), c4 = (int)(i4 & 63);
    const ushort4 u = reinterpret_cast<const ushort4*>(zb)[i4];
    reinterpret_cast<float4*>(grs)[(size_t)row * 192 + c4] =
        make_float4((b2f(u.x) - m) * rs, (b2f(u.y) - m) * rs,
                    (b2f(u.z) - m) * rs, (b2f(u.w) - m) * rs);
}

// vt[g] = sum over graph-g rows of gr slice0 + vn_emb
__global__ __launch_bounds__(256)
void vtsum_kernel(const float* __restrict__ gr, const int* __restrict__ off,
                  const float* __restrict__ vn_emb, float* __restrict__ vt)
{
    const int g = blockIdx.x, t = threadIdx.x;
    const int i0 = off[g], i1 = off[g + 1];
    float s = 0.f;
    for (int i = i0; i < i1; ++i) s += gr[(size_t)i * 768 + t];
    vt[(size_t)g * 256 + t] = s + vn_emb[t];
}

__global__ __launch_bounds__(256)
void vn1_kernel(const float* __restrict__ vt, const float* __restrict__ W,
                const float* __restrict__ b, float* __restrict__ vn1)
{
    __shared__ float row[256];
    const int g = blockIdx.x, t = threadIdx.x;
    row[t] = vt[(size_t)g * 256 + t];
    __syncthreads();
    float a0 = 0.f, a1 = 0.f;
    for (int k = 0; k < 256; ++k) {
        const float rv = row[k];
        a0 = fmaf(rv, W[(size_t)k * 512 + t], a0);
        a1 = fmaf(rv, W[(size_t)k * 512 + 256 + t], a1);
    }
    vn1[(size_t)g * 512 + t]       = fmaxf((a0 + b[t]) * BNS, 0.f);
    vn1[(size_t)g * 512 + 256 + t] = fmaxf((a1 + b[256 + t]) * BNS, 0.f);
}

__global__ __launch_bounds__(256)
void vn2_kernel(const float* __restrict__ vn1, const float* __restrict__ W,
                const float* __restrict__ b, float* __restrict__ vn2)
{
    __shared__ float row[512];
    const int g = blockIdx.x, t = threadIdx.x;
    row[t]       = vn1[(size_t)g * 512 + t];
    row[t + 256] = vn1[(size_t)g * 512 + 256 + t];
    __syncthreads();
    float a = 0.f;
    for (int k = 0; k < 512; ++k) a = fmaf(row[k], W[(size_t)k * 256 + t], a);
    vn2[(size_t)g * 256 + t] = fmaxf((a + b[t]) * BNS, 0.f);
}

// segment max + mean over gr [n x 768] -> readb [NG x 1536] = [max | mean]
__global__ __launch_bounds__(256)
void pool_kernel(const float* __restrict__ gr, const int* __restrict__ off,
                 float* __restrict__ readb)
{
    const int g = blockIdx.x, t = threadIdx.x;
    const int i0 = off[g], i1 = off[g + 1];
    float m0 = -__builtin_inff(), m1 = m0, m2 = m0;
    float s0 = 0.f, s1 = 0.f, s2 = 0.f;
    for (int i = i0; i < i1; ++i) {
        const float* p = gr + (size_t)i * 768;
        const float v0 = p[t], v1 = p[t + 256], v2 = p[t + 512];
        m0 = fmaxf(m0, v0); m1 = fmaxf(m1, v1); m2 = fmaxf(m2, v2);
        s0 += v0; s1 += v1; s2 += v2;
    }
    const float inv = 1.f / fmaxf((float)(i1 - i0), 1.f);
    float* rb = readb + (size_t)g * 1536;
    rb[t] = m0; rb[t + 256] = m1; rb[t + 512] = m2;
    rb[768 + t] = s0 * inv; rb[768 + 256 + t] = s1 * inv; rb[768 + 512 + t] = s2 * inv;
}

// x5 = elu(readb @ loW + lob), 8 graphs per block
__global__ __launch_bounds__(256)
void outg_kernel(const float* __restrict__ readb, const float* __restrict__ W,
                 const float* __restrict__ b, float* __restrict__ x5)
{
    __shared__ float rows[8][1536];
    const int g0 = blockIdx.x * 8, t = threadIdx.x;
    for (int i = t; i < 8 * 1536; i += 256) rows[i / 1536][i % 1536] = readb[(size_t)g0 * 1536 + i];
    __syncthreads();
    float acc[8];
#pragma unroll
    for (int r = 0; r < 8; ++r) acc[r] = 0.f;
    for (int k = 0; k < 1536; ++k) {
        const float wv = W[(size_t)k * 256 + t];
#pragma unroll
        for (int r = 0; r < 8; ++r) acc[r] = fmaf(rows[r][k], wv, acc[r]);
    }
    const float bb = b[t];
#pragma unroll
    for (int r = 0; r < 8; ++r) x5[(size_t)(g0 + r) * 256 + t] = eluf(acc[r] + bb);
}

__global__ __launch_bounds__(64)
void logits_kernel(const float* __restrict__ x5, const float* __restrict__ W,
                   const float* __restrict__ b, float* __restrict__ out)
{
    const int g = blockIdx.x, l = threadIdx.x;
    const float4 v   = reinterpret_cast<const float4*>(x5 + (size_t)g * 256)[l];
    const float4 w01 = reinterpret_cast<const float4*>(W)[l * 2];
    const float4 w23 = reinterpret_cast<const float4*>(W)[l * 2 + 1];
    float p0 = v.x * w01.x + v.y * w01.z + v.z * w23.x + v.w * w23.z;
    float p1 = v.x * w01.y + v.y * w01.w + v.z * w23.y + v.w * w23.w;
    for (int o = 32; o; o >>= 1) { p0 += __shfl_down(p0, o, 64); p1 += __shfl_down(p1, o, 64); }
    if (l == 0) {
        const float z0 = p0 + b[0], z1 = p1 + b[1];
        const float m = fmaxf(z0, z1);
        const float lse = m + logf(expf(z0 - m) + expf(z1 - m));
        out[(size_t)g * 2 + 0] = z0 - lse;
        out[(size_t)g * 2 + 1] = z1 - lse;
    }
}

__global__ __launch_bounds__(192)
void ssl_kernel(const float* __restrict__ x5, const float* __restrict__ dW,
                const float* __restrict__ db, float* __restrict__ out)
{
    const int g = blockIdx.x, t = threadIdx.x;
    const int h = t >> 6, l = t & 63;
    float p = x5[(size_t)g * 256 + h * 64 + l] * dW[h * 64 + l];
    for (int o = 32; o; o >>= 1) p += __shfl_down(p, o, 64);
    if (l == 0) {
        const float z = p + db[h];
        out[(size_t)g * 3 + h] = 0.05f + 0.35f / (1.f + expf(-z));
    }
}

// ---------------------------------------------------------------------------
extern "C" void kernel_launch(void* const* d_in, const int* in_sizes, int n_in,
                              void* d_out, int out_size, void* d_ws, size_t ws_size,
                              hipStream_t stream)
{
    const float* x      = (const float*)d_in[0];
    const int*   eidx   = (const int*)d_in[1];
    const int*   batch  = (const int*)d_in[2];
    const float* lin1_W = (const float*)d_in[3];
    const float* lin1_b = (const float*)d_in[4];
    const float* g0W1   = (const float*)d_in[5];
    const float* g0b1   = (const float*)d_in[6];
    const float* g0W2   = (const float*)d_in[7];
    const float* g0b2   = (const float*)d_in[8];
    const float* g1W1   = (const float*)d_in[9];
    const float* g1b1   = (const float*)d_in[10];
    const float* g1W2   = (const float*)d_in[11];
    const float* g1b2   = (const float*)d_in[12];
    const float* vn_emb = (const float*)d_in[13];
    const float* vnW1   = (const float*)d_in[14];
    const float* vnb1   = (const float*)d_in[15];
    const float* vnW2   = (const float*)d_in[16];
    const float* vnb2   = (const float*)d_in[17];
    const float* loW    = (const float*)d_in[18];
    const float* lob    = (const float*)d_in[19];
    const float* clsW   = (const float*)d_in[20];
    const float* clsb   = (const float*)d_in[21];
    const float* dhW    = (const float*)d_in[22];
    const float* dhb    = (const float*)d_in[23];

    const int N = in_sizes[2];        // 50000 nodes
    const int E = in_sizes[1] / 2;    // 800000 edges
    const int* esrc = eidx;
    const int* edst = eidx + E;

    float* out = (float*)d_out;
    float* out_logits = out;                                     // [NG,2]
    float* out_x5     = out + (size_t)NG * 2;                    // [NG,256]
    float* out_ssl    = out + (size_t)NG * 2 + (size_t)NG * 256; // [NG,3]

    // --- workspace carve (256B aligned slots) ---
    char* p = (char*)d_ws;
    auto carve = [&](size_t bytes) { char* r = p; p += (bytes + 255) & ~(size_t)255; return (void*)r; };
    double* sacc   = (double*)carve(4 * sizeof(double));
    float*  sfin   = (float*) carve(4 * sizeof(float));
    int*    goff   = (int*)   carve((NG + 1) * sizeof(int));
    int*    cnt    = (int*)   carve((size_t)N * sizeof(int));
    int*    rowptr = (int*)   carve((size_t)(N + 1) * sizeof(int));
    int*    cursor = (int*)   carve((size_t)N * sizeof(int));
    int*    es     = (int*)   carve((size_t)E * sizeof(int));
    float*  gr     = (float*) carve((size_t)N * 768 * sizeof(float)); // [gr0|gr1|gr2]
    ushort* xb     = (ushort*)carve((size_t)N * 128 * sizeof(ushort));
    ushort* B1     = (ushort*)carve((size_t)N * 256 * sizeof(ushort));
    ushort* B2     = (ushort*)carve((size_t)N * 256 * sizeof(ushort));
    ushort* B3     = (ushort*)carve((size_t)N * 256 * sizeof(ushort));
    ushort* Wt1    = (ushort*)carve(256 * 128 * sizeof(ushort));
    ushort* Wt0a   = (ushort*)carve(256 * 256 * sizeof(ushort));
    ushort* Wt0b   = (ushort*)carve(256 * 256 * sizeof(ushort));
    ushort* Wtbd1  = (ushort*)carve(16384 * sizeof(ushort));
    ushort* Wtbd2  = (ushort*)carve(16384 * sizeof(ushort));
    float*  vt     = (float*) carve((size_t)NG * 256 * sizeof(float));
    float*  vn1    = (float*) carve((size_t)NG * 512 * sizeof(float));
    float*  vn2    = (float*) carve((size_t)NG * 256 * sizeof(float));
    float*  readb  = (float*) carve((size_t)NG * 1536 * sizeof(float));

    hipMemsetAsync(sacc, 0, 4 * sizeof(double), stream);
    hipMemsetAsync(cnt, 0, (size_t)N * sizeof(int), stream);

    const int mGrid = (N + 63) / 64;
    const int vecGrid = (N * 64 + 255) / 256;
    const int eGrid = (E + 255) / 256;
    const int gatherGrid = (N + 3) / 4;

    // ---- CSR build ----
    count_kernel<<<eGrid, 256, 0, stream>>>(edst, cnt, E);
    scan_kernel<<<1, 1024, 0, stream>>>(cnt, rowptr, N);
    hipMemcpyAsync(cursor, rowptr, (size_t)N * sizeof(int), hipMemcpyDeviceToDevice, stream);
    fill_kernel<<<eGrid, 256, 0, stream>>>(esrc, edst, cursor, es, E);

    // ---- input/weight bf16 prep ----
    cvt_kernel<<<(N * 32 + 255) / 256, 256, 0, stream>>>(x, xb, N * 32);
    wt_dense_kernel<<<(256 * 128 + 255) / 256, 256, 0, stream>>>(lin1_W, Wt1, 128);
    wt_dense_kernel<<<(256 * 256 + 255) / 256, 256, 0, stream>>>(g0W1, Wt0a, 256);
    wt_dense_kernel<<<(256 * 256 + 255) / 256, 256, 0, stream>>>(g0W2, Wt0b, 256);
    wt_bd_kernel<<<64, 256, 0, stream>>>(g1W1, Wtbd1);
    wt_bd_kernel<<<64, 256, 0, stream>>>(g1W2, Wtbd2);

    // h0 = elu(x @ lin1_W + b) -> gr slice0 (f32) + B1 (bf16)
    mgemm_kernel<4, 1, false, false, true, true><<<mGrid, 256, 0, stream>>>(
        xb, 128, Wt1, lin1_b, gr, 768, B1, N, nullptr);
    offsets_kernel<<<3, 256, 0, stream>>>(batch, N, goff);

    // ---- virtual node update (depends only on h0) ----
    vtsum_kernel<<<NG, 256, 0, stream>>>(gr, goff, vn_emb, vt);
    vn1_kernel<<<NG, 256, 0, stream>>>(vt, vnW1, vnb1, vn1);
    vn2_kernel<<<NG, 256, 0, stream>>>(vn1, vnW2, vnb2, vn2);

    // ---- layer 0 ----
    gather0b_kernel<<<gatherGrid, 256, 0, stream>>>(B1, rowptr, es, vn_emb, B2, N);
    mgemm_kernel<8, 0, false, false, false, true><<<mGrid, 256, 0, stream>>>(
        B2, 256, Wt0a, g0b1, nullptr, 0, B3, N, nullptr);
    mgemm_kernel<8, 1, false, true, false, true><<<mGrid, 256, 0, stream>>>(
        B3, 256, Wt0b, g0b2, nullptr, 0, B2, N, sacc);
    finalize_kernel<<<1, 1, 0, stream>>>(sacc, sfin, (double)N * 256.0);
    norm0f_kernel<<<vecGrid, 256, 0, stream>>>(B2, sfin, vn2, batch, gr + 256, B1, N);

    // ---- layer 1 (block-diagonal GIN) ----
    gatherb_kernel<<<gatherGrid, 256, 0, stream>>>(B1, rowptr, es, B2, N);
    mgemm_kernel<2, 0, true, false, false, true><<<mGrid, 256, 0, stream>>>(
        B2, 256, Wtbd1, g1b1, nullptr, 0, B3, N, nullptr);
    mgemm_kernel<2, 1, true, true, false, true><<<mGrid, 256, 0, stream>>>(
        B3, 256, Wtbd2, g1b2, nullptr, 0, B2, N, sacc + 2);
    finalize_kernel<<<1, 1, 0, stream>>>(sacc + 2, sfin + 2, (double)N * 256.0);
    norm1b_kernel<<<vecGrid, 256, 0, stream>>>(B2, sfin + 2, gr + 512, N);

    // ---- readout ----
    pool_kernel<<<NG, 256, 0, stream>>>(gr, goff, readb);
    outg_kernel<<<NG / 8, 256, 0, stream>>>(readb, loW, lob, out_x5);
    logits_kernel<<<NG, 64, 0, stream>>>(out_x5, clsW, clsb, out_logits);
    ssl_kernel<<<NG, 192, 0, stream>>>(out_x5, dhW, dhb, out_ssl);
}

// Round 6
// 878.492 us; speedup vs baseline: 1.4627x; 1.0804x over previous
//
#include <hip/hip_runtime.h>

static constexpr int NG = 512;       // graphs
static constexpr float LN_EPS = 1e-5f;
static constexpr float BNS = 0.9999950000374997f; // rsqrt(1 + 1e-5) for BatchNorm eval

__device__ __forceinline__ float eluf(float v) { return v > 0.f ? v : expm1f(v); }

typedef __attribute__((ext_vector_type(8))) short bf16x8;
typedef __attribute__((ext_vector_type(4))) float f32x4;

__device__ __forceinline__ ushort f2b(float f) {   // f32 -> bf16 RNE
    union { float f; unsigned u; } v; v.f = f;
    const unsigned u = v.u;
    return (ushort)((u + 0x7FFFu + ((u >> 16) & 1u)) >> 16);
}
__device__ __forceinline__ float b2f(ushort b) {
    union { unsigned u; float f; } v; v.u = ((unsigned)b) << 16;
    return v.f;
}

// ---------------------------------------------------------------------------
// W-stationary MFMA GEMM: C[n x 256] = act(A[n x K] @ W + b).
// Block = 4 waves; wave wv owns output cols [wv*64, wv*64+64) = 4 cts.
// B-fragments for the wave's whole K strip live in REGISTERS (loaded once):
//   dense: b[4][KT] (KT = K/32), BD: b[4][2] (chunk == wv).
// Grid-stride over 16-row tiles; per tile: prefetched A-frags + MFMAs only.
// mfma_f32_16x16x32_bf16 layouts (m89-verified):
//   A-frag lane l = A[row0+(l&15)][k0+(l>>4)*8 ..+8]
//   B-frag lane l = Wt[col0+(l&15)][k0+(l>>4)*8 ..+8]
//   D lane l reg r = C[row0+(l>>4)*4+r][col0+(l&15)]
// ---------------------------------------------------------------------------
template<int KT, int ACT, bool BD, bool STATS, bool WF32, bool WB16>
__global__ __launch_bounds__(256, 2)
void wgemm_kernel(const ushort* __restrict__ Ab, int ldab,
                  const ushort* __restrict__ Wt,
                  const float* __restrict__ bias,
                  float* __restrict__ Cf, int ldc,
                  ushort* __restrict__ Cb,
                  int n, double* __restrict__ stats)
{
    constexpr int KTe = BD ? 2 : KT;
    const int lane = threadIdx.x & 63;
    const int wv = threadIdx.x >> 6;
    const int koff = (lane >> 4) * 8;
    const int colL = lane & 15;
    const int akbase = BD ? wv * 64 : 0;

    // ---- persistent B fragments + bias (loaded once per wave) ----
    bf16x8 b[4][KTe];
    float bv[4];
#pragma unroll
    for (int ct = 0; ct < 4; ++ct) {
        const ushort* wp = BD
            ? Wt + wv * 4096 + (ct * 16 + colL) * 64 + koff
            : Wt + (size_t)(wv * 64 + ct * 16 + colL) * (KT * 32) + koff;
#pragma unroll
        for (int kk = 0; kk < KTe; ++kk)
            b[ct][kk] = *reinterpret_cast<const bf16x8*>(wp + kk * 32);
        bv[ct] = bias[wv * 64 + ct * 16 + colL];
    }

    const int ntiles = (n + 15) >> 4;
    float s = 0.f, ss = 0.f;

    int tile = (int)blockIdx.x;
    bf16x8 af[KTe];
    if (tile < ntiles) {
        const int rA = min(tile * 16 + colL, n - 1);
        const ushort* ap = Ab + (size_t)rA * ldab + akbase + koff;
#pragma unroll
        for (int kk = 0; kk < KTe; ++kk)
            af[kk] = *reinterpret_cast<const bf16x8*>(ap + kk * 32);
    }

    for (; tile < ntiles; tile += gridDim.x) {
        // prefetch next tile's A-frags
        const int nt = tile + (int)gridDim.x;
        bf16x8 nf[KTe];
        if (nt < ntiles) {
            const int rA = min(nt * 16 + colL, n - 1);
            const ushort* ap = Ab + (size_t)rA * ldab + akbase + koff;
#pragma unroll
            for (int kk = 0; kk < KTe; ++kk)
                nf[kk] = *reinterpret_cast<const bf16x8*>(ap + kk * 32);
        }

        f32x4 acc[4];
#pragma unroll
        for (int ct = 0; ct < 4; ++ct) acc[ct] = (f32x4){0.f, 0.f, 0.f, 0.f};
#pragma unroll
        for (int kk = 0; kk < KTe; ++kk)
#pragma unroll
            for (int ct = 0; ct < 4; ++ct)
                acc[ct] = __builtin_amdgcn_mfma_f32_16x16x32_bf16(af[kk], b[ct][kk], acc[ct], 0, 0, 0);

        const int r0 = tile * 16 + ((lane >> 4) << 2);
#pragma unroll
        for (int ct = 0; ct < 4; ++ct) {
            const int col = wv * 64 + ct * 16 + colL;
#pragma unroll
            for (int r = 0; r < 4; ++r) {
                const int row = r0 + r;
                if (row < n) {
                    float v = acc[ct][r] + bv[ct];
                    v = (ACT == 0) ? fmaxf(v, 0.f) : eluf(v);
                    if constexpr (WF32) Cf[(size_t)row * ldc + col] = v;
                    if constexpr (WB16) Cb[(size_t)row * 256 + col] = f2b(v);
                    if constexpr (STATS) { s += v; ss += v * v; }
                }
            }
        }
#pragma unroll
        for (int kk = 0; kk < KTe; ++kk) af[kk] = nf[kk];
    }

    if constexpr (STATS) {
        double ds = (double)s, dss = (double)ss;
        for (int o = 32; o; o >>= 1) { ds += __shfl_down(ds, o, 64); dss += __shfl_down(dss, o, 64); }
        if (lane == 0) { unsafeAtomicAdd(&stats[0], ds); unsafeAtomicAdd(&stats[1], dss); }
    }
}

// ---------------------------------------------------------------------------
// Weight prep: f32 -> bf16 transposed
// ---------------------------------------------------------------------------
__global__ void wt_dense_kernel(const float* __restrict__ W, ushort* __restrict__ Wt, int K)
{
    const int idx = blockIdx.x * 256 + threadIdx.x;
    if (idx >= 256 * K) return;
    const int c = idx / K, k = idx - c * K;
    Wt[idx] = f2b(W[(size_t)k * 256 + c]);
}

__global__ void wt_bd_kernel(const float* __restrict__ W, ushort* __restrict__ Wt)
{
    const int idx = blockIdx.x * 256 + threadIdx.x;
    if (idx >= 16384) return;
    const int ch = idx >> 12, r = idx & 4095, cw = r >> 6, k = r & 63;
    Wt[idx] = f2b(W[ch * 4096 + k * 64 + cw]);
}

__global__ void cvt_kernel(const float* __restrict__ in, ushort* __restrict__ out, int n4)
{
    const int i = blockIdx.x * 256 + threadIdx.x;
    if (i >= n4) return;
    const float4 v = reinterpret_cast<const float4*>(in)[i];
    reinterpret_cast<ushort4*>(out)[i] = make_ushort4(f2b(v.x), f2b(v.y), f2b(v.z), f2b(v.w));
}

// ---------------------------------------------------------------------------
// CSR construction (by destination), rebuilt every call
// ---------------------------------------------------------------------------
__global__ void count_kernel(const int* __restrict__ dst, int* __restrict__ cnt, int nE)
{
    const int e = blockIdx.x * 256 + threadIdx.x;
    if (e < nE) atomicAdd(&cnt[dst[e]], 1);
}

__global__ __launch_bounds__(1024)
void scan_kernel(const int* __restrict__ cnt, int* __restrict__ rowptr, int n)
{
    __shared__ int part[1024];
    const int t = threadIdx.x;
    const int chunk = (n + 1023) / 1024;
    const int i0 = min(t * chunk, n), i1 = min(i0 + chunk, n);
    int s = 0;
    for (int i = i0; i < i1; ++i) s += cnt[i];
    part[t] = s;
    __syncthreads();
    for (int o = 1; o < 1024; o <<= 1) {
        const int v = (t >= o) ? part[t - o] : 0;
        __syncthreads();
        part[t] += v;
        __syncthreads();
    }
    int base = (t == 0) ? 0 : part[t - 1];
    for (int i = i0; i < i1; ++i) { rowptr[i] = base; base += cnt[i]; }
    if (t == 1023) rowptr[n] = part[1023];
}

__global__ void fill_kernel(const int* __restrict__ src, const int* __restrict__ dst,
                            int* __restrict__ cursor, int* __restrict__ es, int nE)
{
    const int e = blockIdx.x * 256 + threadIdx.x;
    if (e >= nE) return;
    const int p = atomicAdd(&cursor[dst[e]], 1);
    es[p] = src[e];
}

// ---------------------------------------------------------------------------
// Layer-0 gather (vn fold): ob[i] = bf16( 2*h_i + (2+deg_i)*vn + sum_j h_j )
// ---------------------------------------------------------------------------
__global__ __launch_bounds__(256)
void gather0b_kernel(const ushort* __restrict__ hb, const int* __restrict__ rowptr,
                     const int* __restrict__ es, const float* __restrict__ vn_emb,
                     ushort* __restrict__ ob, int n)
{
    const int node = blockIdx.x * 4 + (threadIdx.x >> 6);
    if (node >= n) return;
    const int lane = threadIdx.x & 63;
    const ushort4* H4 = reinterpret_cast<const ushort4*>(hb);
    const ushort4 o = H4[(size_t)node * 64 + lane];
    const int b = rowptr[node], e = rowptr[node + 1];
    const float4 vn = reinterpret_cast<const float4*>(vn_emb)[lane];
    const float cv = (float)(2 + (e - b));
    float a0 = fmaf(cv, vn.x, 2.f * b2f(o.x));
    float a1 = fmaf(cv, vn.y, 2.f * b2f(o.y));
    float a2 = fmaf(cv, vn.z, 2.f * b2f(o.z));
    float a3 = fmaf(cv, vn.w, 2.f * b2f(o.w));
    int i = b;
    for (; i + 2 <= e; i += 2) {
        const ushort4 v0 = H4[(size_t)es[i] * 64 + lane];
        const ushort4 v1 = H4[(size_t)es[i + 1] * 64 + lane];
        a0 += b2f(v0.x) + b2f(v1.x);
        a1 += b2f(v0.y) + b2f(v1.y);
        a2 += b2f(v0.z) + b2f(v1.z);
        a3 += b2f(v0.w) + b2f(v1.w);
    }
    for (; i < e; ++i) {
        const ushort4 v = H4[(size_t)es[i] * 64 + lane];
        a0 += b2f(v.x); a1 += b2f(v.y); a2 += b2f(v.z); a3 += b2f(v.w);
    }
    reinterpret_cast<ushort4*>(ob)[(size_t)node * 64 + lane] =
        make_ushort4(f2b(a0), f2b(a1), f2b(a2), f2b(a3));
}

// Generic gather: ob[i] = bf16( 2*t_i + sum_j t_j )
__global__ __launch_bounds__(256)
void gatherb_kernel(const ushort* __restrict__ tb, const int* __restrict__ rowptr,
                    const int* __restrict__ es, ushort* __restrict__ ob, int n)
{
    const int node = blockIdx.x * 4 + (threadIdx.x >> 6);
    if (node >= n) return;
    const int lane = threadIdx.x & 63;
    const ushort4* H4 = reinterpret_cast<const ushort4*>(tb);
    const ushort4 o = H4[(size_t)node * 64 + lane];
    float a0 = 2.f * b2f(o.x), a1 = 2.f * b2f(o.y), a2 = 2.f * b2f(o.z), a3 = 2.f * b2f(o.w);
    const int b = rowptr[node], e = rowptr[node + 1];
    int i = b;
    for (; i + 2 <= e; i += 2) {
        const ushort4 v0 = H4[(size_t)es[i] * 64 + lane];
        const ushort4 v1 = H4[(size_t)es[i + 1] * 64 + lane];
        a0 += b2f(v0.x) + b2f(v1.x);
        a1 += b2f(v0.y) + b2f(v1.y);
        a2 += b2f(v0.z) + b2f(v1.z);
        a3 += b2f(v0.w) + b2f(v1.w);
    }
    for (; i < e; ++i) {
        const ushort4 v = H4[(size_t)es[i] * 64 + lane];
        a0 += b2f(v.x); a1 += b2f(v.y); a2 += b2f(v.z); a3 += b2f(v.w);
    }
    reinterpret_cast<ushort4*>(ob)[(size_t)node * 64 + lane] =
        make_ushort4(f2b(a0), f2b(a1), f2b(a2), f2b(a3));
}

// Graph boundaries (batch is sorted)
__global__ void offsets_kernel(const int* __restrict__ batch, int n, int* __restrict__ off)
{
    const int g = blockIdx.x * blockDim.x + threadIdx.x;
    if (g > NG) return;
    int lo = 0, hi = n;
    while (lo < hi) { const int mid = (lo + hi) >> 1; if (batch[mid] < g) lo = mid + 1; else hi = mid; }
    off[g] = lo;
}

__global__ void finalize_kernel(const double* __restrict__ sacc, float* __restrict__ sfin, double M)
{
    const double mean = sacc[0] / M;
    double var = sacc[1] / M - mean * mean;
    if (var < 0.0) var = 0.0;
    sfin[0] = (float)mean;
    sfin[1] = (float)(1.0 / sqrt(var + (double)LN_EPS));
}

// LN normalize (bf16 in), write gr slice f32 AND bf16(z + vn2[batch]) for layer 1
__global__ void norm0f_kernel(const ushort* __restrict__ zb, const float* __restrict__ sfin,
                              const float* __restrict__ vn2, const int* __restrict__ batch,
                              float* __restrict__ grs, ushort* __restrict__ tb, int n)
{
    const size_t i4 = (size_t)blockIdx.x * blockDim.x + threadIdx.x;
    if (i4 >= (size_t)n * 64) return;
    const float m = sfin[0], rs = sfin[1];
    const int row = (int)(i4 >> 6), c4 = (int)(i4 & 63);
    const ushort4 u = reinterpret_cast<const ushort4*>(zb)[i4];
    const float z0 = (b2f(u.x) - m) * rs, z1 = (b2f(u.y) - m) * rs,
                z2 = (b2f(u.z) - m) * rs, z3 = (b2f(u.w) - m) * rs;
    reinterpret_cast<float4*>(grs)[(size_t)row * 192 + c4] = make_float4(z0, z1, z2, z3);
    const int g = batch[row];
    const float4 e = reinterpret_cast<const float4*>(vn2 + (size_t)g * 256)[c4];
    reinterpret_cast<ushort4*>(tb)[i4] =
        make_ushort4(f2b(z0 + e.x), f2b(z1 + e.y), f2b(z2 + e.z), f2b(z3 + e.w));
}

// LN normalize (bf16 in), write gr slice f32 only
__global__ void norm1b_kernel(const ushort* __restrict__ zb, const float* __restrict__ sfin,
                              float* __restrict__ grs, int n)
{
    const size_t i4 = (size_t)blockIdx.x * blockDim.x + threadIdx.x;
    if (i4 >= (size_t)n * 64) return;
    const float m = sfin[0], rs = sfin[1];
    const int row = (int)(i4 >> 6), c4 = (int)(i4 & 63);
    const ushort4 u = reinterpret_cast<const ushort4*>(zb)[i4];
    reinterpret_cast<float4*>(grs)[(size_t)row * 192 + c4] =
        make_float4((b2f(u.x) - m) * rs, (b2f(u.y) - m) * rs,
                    (b2f(u.z) - m) * rs, (b2f(u.w) - m) * rs);
}

// vt[g] = sum over graph-g rows of gr slice0 + vn_emb
__global__ __launch_bounds__(256)
void vtsum_kernel(const float* __restrict__ gr, const int* __restrict__ off,
                  const float* __restrict__ vn_emb, float* __restrict__ vt)
{
    const int g = blockIdx.x, t = threadIdx.x;
    const int i0 = off[g], i1 = off[g + 1];
    float s = 0.f;
    for (int i = i0; i < i1; ++i) s += gr[(size_t)i * 768 + t];
    vt[(size_t)g * 256 + t] = s + vn_emb[t];
}

__global__ __launch_bounds__(256)
void vn1_kernel(const float* __restrict__ vt, const float* __restrict__ W,
                const float* __restrict__ b, float* __restrict__ vn1)
{
    __shared__ float row[256];
    const int g = blockIdx.x, t = threadIdx.x;
    row[t] = vt[(size_t)g * 256 + t];
    __syncthreads();
    float a0 = 0.f, a1 = 0.f;
    for (int k = 0; k < 256; ++k) {
        const float rv = row[k];
        a0 = fmaf(rv, W[(size_t)k * 512 + t], a0);
        a1 = fmaf(rv, W[(size_t)k * 512 + 256 + t], a1);
    }
    vn1[(size_t)g * 512 + t]       = fmaxf((a0 + b[t]) * BNS, 0.f);
    vn1[(size_t)g * 512 + 256 + t] = fmaxf((a1 + b[256 + t]) * BNS, 0.f);
}

__global__ __launch_bounds__(256)
void vn2_kernel(const float* __restrict__ vn1, const float* __restrict__ W,
                const float* __restrict__ b, float* __restrict__ vn2)
{
    __shared__ float row[512];
    const int g = blockIdx.x, t = threadIdx.x;
    row[t]       = vn1[(size_t)g * 512 + t];
    row[t + 256] = vn1[(size_t)g * 512 + 256 + t];
    __syncthreads();
    float a = 0.f;
    for (int k = 0; k < 512; ++k) a = fmaf(row[k], W[(size_t)k * 256 + t], a);
    vn2[(size_t)g * 256 + t] = fmaxf((a + b[t]) * BNS, 0.f);
}

// segment max + mean over gr [n x 768] -> readb [NG x 1536] = [max | mean]
__global__ __launch_bounds__(256)
void pool_kernel(const float* __restrict__ gr, const int* __restrict__ off,
                 float* __restrict__ readb)
{
    const int g = blockIdx.x, t = threadIdx.x;
    const int i0 = off[g], i1 = off[g + 1];
    float m0 = -__builtin_inff(), m1 = m0, m2 = m0;
    float s0 = 0.f, s1 = 0.f, s2 = 0.f;
    for (int i = i0; i < i1; ++i) {
        const float* p = gr + (size_t)i * 768;
        const float v0 = p[t], v1 = p[t + 256], v2 = p[t + 512];
        m0 = fmaxf(m0, v0); m1 = fmaxf(m1, v1); m2 = fmaxf(m2, v2);
        s0 += v0; s1 += v1; s2 += v2;
    }
    const float inv = 1.f / fmaxf((float)(i1 - i0), 1.f);
    float* rb = readb + (size_t)g * 1536;
    rb[t] = m0; rb[t + 256] = m1; rb[t + 512] = m2;
    rb[768 + t] = s0 * inv; rb[768 + 256 + t] = s1 * inv; rb[768 + 512 + t] = s2 * inv;
}

// x5 = elu(readb @ loW + lob), 8 graphs per block
__global__ __launch_bounds__(256)
void outg_kernel(const float* __restrict__ readb, const float* __restrict__ W,
                 const float* __restrict__ b, float* __restrict__ x5)
{
    __shared__ float rows[8][1536];
    const int g0 = blockIdx.x * 8, t = threadIdx.x;
    for (int i = t; i < 8 * 1536; i += 256) rows[i / 1536][i % 1536] = readb[(size_t)g0 * 1536 + i];
    __syncthreads();
    float acc[8];
#pragma unroll
    for (int r = 0; r < 8; ++r) acc[r] = 0.f;
    for (int k = 0; k < 1536; ++k) {
        const float wv = W[(size_t)k * 256 + t];
#pragma unroll
        for (int r = 0; r < 8; ++r) acc[r] = fmaf(rows[r][k], wv, acc[r]);
    }
    const float bb = b[t];
#pragma unroll
    for (int r = 0; r < 8; ++r) x5[(size_t)(g0 + r) * 256 + t] = eluf(acc[r] + bb);
}

__global__ __launch_bounds__(64)
void logits_kernel(const float* __restrict__ x5, const float* __restrict__ W,
                   const float* __restrict__ b, float* __restrict__ out)
{
    const int g = blockIdx.x, l = threadIdx.x;
    const float4 v   = reinterpret_cast<const float4*>(x5 + (size_t)g * 256)[l];
    const float4 w01 = reinterpret_cast<const float4*>(W)[l * 2];
    const float4 w23 = reinterpret_cast<const float4*>(W)[l * 2 + 1];
    float p0 = v.x * w01.x + v.y * w01.z + v.z * w23.x + v.w * w23.z;
    float p1 = v.x * w01.y + v.y * w01.w + v.z * w23.y + v.w * w23.w;
    for (int o = 32; o; o >>= 1) { p0 += __shfl_down(p0, o, 64); p1 += __shfl_down(p1, o, 64); }
    if (l == 0) {
        const float z0 = p0 + b[0], z1 = p1 + b[1];
        const float m = fmaxf(z0, z1);
        const float lse = m + logf(expf(z0 - m) + expf(z1 - m));
        out[(size_t)g * 2 + 0] = z0 - lse;
        out[(size_t)g * 2 + 1] = z1 - lse;
    }
}

__global__ __launch_bounds__(192)
void ssl_kernel(const float* __restrict__ x5, const float* __restrict__ dW,
                const float* __restrict__ db, float* __restrict__ out)
{
    const int g = blockIdx.x, t = threadIdx.x;
    const int h = t >> 6, l = t & 63;
    float p = x5[(size_t)g * 256 + h * 64 + l] * dW[h * 64 + l];
    for (int o = 32; o; o >>= 1) p += __shfl_down(p, o, 64);
    if (l == 0) {
        const float z = p + db[h];
        out[(size_t)g * 3 + h] = 0.05f + 0.35f / (1.f + expf(-z));
    }
}

// ---------------------------------------------------------------------------
extern "C" void kernel_launch(void* const* d_in, const int* in_sizes, int n_in,
                              void* d_out, int out_size, void* d_ws, size_t ws_size,
                              hipStream_t stream)
{
    const float* x      = (const float*)d_in[0];
    const int*   eidx   = (const int*)d_in[1];
    const int*   batch  = (const int*)d_in[2];
    const float* lin1_W = (const float*)d_in[3];
    const float* lin1_b = (const float*)d_in[4];
    const float* g0W1   = (const float*)d_in[5];
    const float* g0b1   = (const float*)d_in[6];
    const float* g0W2   = (const float*)d_in[7];
    const float* g0b2   = (const float*)d_in[8];
    const float* g1W1   = (const float*)d_in[9];
    const float* g1b1   = (const float*)d_in[10];
    const float* g1W2   = (const float*)d_in[11];
    const float* g1b2   = (const float*)d_in[12];
    const float* vn_emb = (const float*)d_in[13];
    const float* vnW1   = (const float*)d_in[14];
    const float* vnb1   = (const float*)d_in[15];
    const float* vnW2   = (const float*)d_in[16];
    const float* vnb2   = (const float*)d_in[17];
    const float* loW    = (const float*)d_in[18];
    const float* lob    = (const float*)d_in[19];
    const float* clsW   = (const float*)d_in[20];
    const float* clsb   = (const float*)d_in[21];
    const float* dhW    = (const float*)d_in[22];
    const float* dhb    = (const float*)d_in[23];

    const int N = in_sizes[2];        // 50000 nodes
    const int E = in_sizes[1] / 2;    // 800000 edges
    const int* esrc = eidx;
    const int* edst = eidx + E;

    float* out = (float*)d_out;
    float* out_logits = out;                                     // [NG,2]
    float* out_x5     = out + (size_t)NG * 2;                    // [NG,256]
    float* out_ssl    = out + (size_t)NG * 2 + (size_t)NG * 256; // [NG,3]

    // --- workspace carve (256B aligned slots) ---
    char* p = (char*)d_ws;
    auto carve = [&](size_t bytes) { char* r = p; p += (bytes + 255) & ~(size_t)255; return (void*)r; };
    double* sacc   = (double*)carve(4 * sizeof(double));
    float*  sfin   = (float*) carve(4 * sizeof(float));
    int*    goff   = (int*)   carve((NG + 1) * sizeof(int));
    int*    cnt    = (int*)   carve((size_t)N * sizeof(int));
    int*    rowptr = (int*)   carve((size_t)(N + 1) * sizeof(int));
    int*    cursor = (int*)   carve((size_t)N * sizeof(int));
    int*    es     = (int*)   carve((size_t)E * sizeof(int));
    float*  gr     = (float*) carve((size_t)N * 768 * sizeof(float)); // [gr0|gr1|gr2]
    ushort* xb     = (ushort*)carve((size_t)N * 128 * sizeof(ushort));
    ushort* B1     = (ushort*)carve((size_t)N * 256 * sizeof(ushort));
    ushort* B2     = (ushort*)carve((size_t)N * 256 * sizeof(ushort));
    ushort* B3     = (ushort*)carve((size_t)N * 256 * sizeof(ushort));
    ushort* Wt1    = (ushort*)carve(256 * 128 * sizeof(ushort));
    ushort* Wt0a   = (ushort*)carve(256 * 256 * sizeof(ushort));
    ushort* Wt0b   = (ushort*)carve(256 * 256 * sizeof(ushort));
    ushort* Wtbd1  = (ushort*)carve(16384 * sizeof(ushort));
    ushort* Wtbd2  = (ushort*)carve(16384 * sizeof(ushort));
    float*  vt     = (float*) carve((size_t)NG * 256 * sizeof(float));
    float*  vn1    = (float*) carve((size_t)NG * 512 * sizeof(float));
    float*  vn2    = (float*) carve((size_t)NG * 256 * sizeof(float));
    float*  readb  = (float*) carve((size_t)NG * 1536 * sizeof(float));

    hipMemsetAsync(sacc, 0, 4 * sizeof(double), stream);
    hipMemsetAsync(cnt, 0, (size_t)N * sizeof(int), stream);

    const int ntiles = (N + 15) / 16;
    const int wGrid = ntiles < 1024 ? ntiles : 1024;
    const int vecGrid = (N * 64 + 255) / 256;
    const int eGrid = (E + 255) / 256;
    const int gatherGrid = (N + 3) / 4;

    // ---- CSR build ----
    count_kernel<<<eGrid, 256, 0, stream>>>(edst, cnt, E);
    scan_kernel<<<1, 1024, 0, stream>>>(cnt, rowptr, N);
    hipMemcpyAsync(cursor, rowptr, (size_t)N * sizeof(int), hipMemcpyDeviceToDevice, stream);
    fill_kernel<<<eGrid, 256, 0, stream>>>(esrc, edst, cursor, es, E);

    // ---- input/weight bf16 prep ----
    cvt_kernel<<<(N * 32 + 255) / 256, 256, 0, stream>>>(x, xb, N * 32);
    wt_dense_kernel<<<(256 * 128 + 255) / 256, 256, 0, stream>>>(lin1_W, Wt1, 128);
    wt_dense_kernel<<<(256 * 256 + 255) / 256, 256, 0, stream>>>(g0W1, Wt0a, 256);
    wt_dense_kernel<<<(256 * 256 + 255) / 256, 256, 0, stream>>>(g0W2, Wt0b, 256);
    wt_bd_kernel<<<64, 256, 0, stream>>>(g1W1, Wtbd1);
    wt_bd_kernel<<<64, 256, 0, stream>>>(g1W2, Wtbd2);

    // h0 = elu(x @ lin1_W + b) -> gr slice0 (f32) + B1 (bf16)
    wgemm_kernel<4, 1, false, false, true, true><<<wGrid, 256, 0, stream>>>(
        xb, 128, Wt1, lin1_b, gr, 768, B1, N, nullptr);
    offsets_kernel<<<3, 256, 0, stream>>>(batch, N, goff);

    // ---- virtual node update (depends only on h0) ----
    vtsum_kernel<<<NG, 256, 0, stream>>>(gr, goff, vn_emb, vt);
    vn1_kernel<<<NG, 256, 0, stream>>>(vt, vnW1, vnb1, vn1);
    vn2_kernel<<<NG, 256, 0, stream>>>(vn1, vnW2, vnb2, vn2);

    // ---- layer 0 ----
    gather0b_kernel<<<gatherGrid, 256, 0, stream>>>(B1, rowptr, es, vn_emb, B2, N);
    wgemm_kernel<8, 0, false, false, false, true><<<wGrid, 256, 0, stream>>>(
        B2, 256, Wt0a, g0b1, nullptr, 0, B3, N, nullptr);
    wgemm_kernel<8, 1, false, true, false, true><<<wGrid, 256, 0, stream>>>(
        B3, 256, Wt0b, g0b2, nullptr, 0, B2, N, sacc);
    finalize_kernel<<<1, 1, 0, stream>>>(sacc, sfin, (double)N * 256.0);
    norm0f_kernel<<<vecGrid, 256, 0, stream>>>(B2, sfin, vn2, batch, gr + 256, B1, N);

    // ---- layer 1 (block-diagonal GIN) ----
    gatherb_kernel<<<gatherGrid, 256, 0, stream>>>(B1, rowptr, es, B2, N);
    wgemm_kernel<8, 0, true, false, false, true><<<wGrid, 256, 0, stream>>>(
        B2, 256, Wtbd1, g1b1, nullptr, 0, B3, N, nullptr);
    wgemm_kernel<8, 1, true, true, false, true><<<wGrid, 256, 0, stream>>>(
        B3, 256, Wtbd2, g1b2, nullptr, 0, B2, N, sacc + 2);
    finalize_kernel<<<1, 1, 0, stream>>>(sacc + 2, sfin + 2, (double)N * 256.0);
    norm1b_kernel<<<vecGrid, 256, 0, stream>>>(B2, sfin + 2, gr + 512, N);

    // ---- readout ----
    pool_kernel<<<NG, 256, 0, stream>>>(gr, goff, readb);
    outg_kernel<<<NG / 8, 256, 0, stream>>>(readb, loW, lob, out_x5);
    logits_kernel<<<NG, 64, 0, stream>>>(out_x5, clsW, clsb, out_logits);
    ssl_kernel<<<NG, 192, 0, stream>>>(out_x5, dhW, dhb, out_ssl);
}